// Round 1
// baseline (240.462 us; speedup 1.0000x reference)
//
#include <hip/hip_runtime.h>
#include <hip/hip_bf16.h>

#define FEAT_DIM 512
#define BATCH 256

// ws layout: [0] float total; [16..16+256*4) float lse[256]
__global__ __launch_bounds__(64) void centerloss_rowstats(
    const float* __restrict__ feats,
    const float* __restrict__ centers,
    const int* __restrict__ labels,
    float* __restrict__ total,
    float* __restrict__ lse) {
    const int row = blockIdx.x;          // 0..255
    const int lane = threadIdx.x;        // 0..63, one wave per row

    const float4* f4 = (const float4*)(feats + (size_t)row * FEAT_DIM);
    const int lbl = labels[row];
    const float4* c4 = (const float4*)(centers + (size_t)lbl * FEAT_DIM);

    // each lane: 8 contiguous floats (two float4) at offset lane*8
    float4 fa = f4[lane * 2];
    float4 fb = f4[lane * 2 + 1];
    float4 ca = c4[lane * 2];
    float4 cb = c4[lane * 2 + 1];

    float f[8] = {fa.x, fa.y, fa.z, fa.w, fb.x, fb.y, fb.z, fb.w};
    float c[8] = {ca.x, ca.y, ca.z, ca.w, cb.x, cb.y, cb.z, cb.w};

    float d = 0.f;
    float m = -INFINITY;
#pragma unroll
    for (int k = 0; k < 8; ++k) {
        float t = f[k] - c[k];
        d += t * t;
        m = fmaxf(m, f[k]);
    }

    // wave64 butterfly: reduce d (sum) and m (max) together
#pragma unroll
    for (int off = 32; off >= 1; off >>= 1) {
        d += __shfl_xor(d, off, 64);
        m = fmaxf(m, __shfl_xor(m, off, 64));
    }

    float s = 0.f;
#pragma unroll
    for (int k = 0; k < 8; ++k) s += __expf(f[k] - m);
#pragma unroll
    for (int off = 32; off >= 1; off >>= 1) s += __shfl_xor(s, off, 64);

    if (lane == 0) {
        lse[row] = m + __logf(s);
        atomicAdd(total, d);
    }
}

__global__ __launch_bounds__(256) void centerloss_write(
    const float* __restrict__ feats,
    const float* __restrict__ total,
    const float* __restrict__ lse,
    float* __restrict__ out) {
    const int idx = blockIdx.x * blockDim.x + threadIdx.x;  // float4 index, 0..32767
    const int row = idx >> 7;                               // 128 float4 per row
    const float t = *total;
    const float l = lse[row];
    const float add = t - l;
    float4 f = ((const float4*)feats)[idx];
    float4 o;
    o.x = f.x + add;
    o.y = f.y + add;
    o.z = f.z + add;
    o.w = f.w + add;
    ((float4*)out)[idx] = o;
}

extern "C" void kernel_launch(void* const* d_in, const int* in_sizes, int n_in,
                              void* d_out, int out_size, void* d_ws, size_t ws_size,
                              hipStream_t stream) {
    const float* feats   = (const float*)d_in[0];
    const float* centers = (const float*)d_in[1];
    const int*   labels  = (const int*)d_in[2];
    float* out = (float*)d_out;

    float* total = (float*)d_ws;
    float* lse   = (float*)((char*)d_ws + 16);

    hipMemsetAsync(total, 0, sizeof(float), stream);

    centerloss_rowstats<<<BATCH, 64, 0, stream>>>(feats, centers, labels, total, lse);

    const int n4 = BATCH * FEAT_DIM / 4;  // 32768
    centerloss_write<<<n4 / 256, 256, 0, stream>>>(feats, total, lse, out);
}

// Round 2
// 232.327 us; speedup vs baseline: 1.0350x; 1.0350x over previous
//
#include <hip/hip_runtime.h>
#include <hip/hip_bf16.h>

#define FEAT_DIM 512
#define BATCH 256

// ws layout: float dist[256] @ 0, float lse[256] @ 1024 bytes
__global__ __launch_bounds__(64) void centerloss_rowstats(
    const float* __restrict__ feats,
    const float* __restrict__ centers,
    const int* __restrict__ labels,
    float* __restrict__ dist,
    float* __restrict__ lse) {
    const int row = blockIdx.x;          // 0..255
    const int lane = threadIdx.x;        // 0..63, one wave per row

    const float4* f4 = (const float4*)(feats + (size_t)row * FEAT_DIM);
    const int lbl = labels[row];
    const float4* c4 = (const float4*)(centers + (size_t)lbl * FEAT_DIM);

    // each lane: 8 contiguous floats (two float4) at offset lane*8
    float4 fa = f4[lane * 2];
    float4 fb = f4[lane * 2 + 1];
    float4 ca = c4[lane * 2];
    float4 cb = c4[lane * 2 + 1];

    float f[8] = {fa.x, fa.y, fa.z, fa.w, fb.x, fb.y, fb.z, fb.w};
    float c[8] = {ca.x, ca.y, ca.z, ca.w, cb.x, cb.y, cb.z, cb.w};

    float d = 0.f;
    float m = -INFINITY;
#pragma unroll
    for (int k = 0; k < 8; ++k) {
        float t = f[k] - c[k];
        d += t * t;
        m = fmaxf(m, f[k]);
    }

    // wave64 butterfly: reduce d (sum) and m (max) together
#pragma unroll
    for (int off = 32; off >= 1; off >>= 1) {
        d += __shfl_xor(d, off, 64);
        m = fmaxf(m, __shfl_xor(m, off, 64));
    }

    float s = 0.f;
#pragma unroll
    for (int k = 0; k < 8; ++k) s += __expf(f[k] - m);
#pragma unroll
    for (int off = 32; off >= 1; off >>= 1) s += __shfl_xor(s, off, 64);

    if (lane == 0) {
        dist[row] = d;
        lse[row] = m + __logf(s);
    }
}

__global__ __launch_bounds__(256) void centerloss_write(
    const float* __restrict__ feats,
    const float* __restrict__ dist,
    const float* __restrict__ lse,
    float* __restrict__ out) {
    const int tid = threadIdx.x;                 // 0..255
    const int idx = blockIdx.x * 256 + tid;      // float4 index, 0..32767
    const int row = idx >> 7;                    // 128 float4 per row

    // every block redundantly reduces the 256 dists (1 KB, L2-hot)
    float v = dist[tid];
#pragma unroll
    for (int off = 32; off >= 1; off >>= 1) v += __shfl_xor(v, off, 64);

    __shared__ float part[4];
    if ((tid & 63) == 0) part[tid >> 6] = v;
    __syncthreads();
    const float total = part[0] + part[1] + part[2] + part[3];

    const float add = total - lse[row];
    float4 f = ((const float4*)feats)[idx];
    float4 o;
    o.x = f.x + add;
    o.y = f.y + add;
    o.z = f.z + add;
    o.w = f.w + add;
    ((float4*)out)[idx] = o;
}

extern "C" void kernel_launch(void* const* d_in, const int* in_sizes, int n_in,
                              void* d_out, int out_size, void* d_ws, size_t ws_size,
                              hipStream_t stream) {
    const float* feats   = (const float*)d_in[0];
    const float* centers = (const float*)d_in[1];
    const int*   labels  = (const int*)d_in[2];
    float* out = (float*)d_out;

    float* dist = (float*)d_ws;
    float* lse  = (float*)((char*)d_ws + 1024);

    centerloss_rowstats<<<BATCH, 64, 0, stream>>>(feats, centers, labels, dist, lse);

    const int n4 = BATCH * FEAT_DIM / 4;  // 32768
    centerloss_write<<<n4 / 256, 256, 0, stream>>>(feats, dist, lse, out);
}